// Round 10
// baseline (484.926 us; speedup 1.0000x reference)
//
#include <hip/hip_runtime.h>
#include <math.h>

#define HID 128
#define G3  384
#define BATCH 256
#define SEQ 512
#define NB 16            // batch tile per scan block
#define NBLK (BATCH/NB)  // 16 scan blocks

typedef __bf16 bf16x8 __attribute__((ext_vector_type(8)));
typedef __bf16 bf16x4 __attribute__((ext_vector_type(4)));
typedef float  f32x4  __attribute__((ext_vector_type(4)));

#define LOG2E 1.44269504088896f
// gate scales folded into weights/biases: r,z: -log2e ; n: -2*log2e
#define SC_RZ (-1.44269504088896f)
#define SC_N  (-2.88539008177793f)

__device__ __forceinline__ float sigm(float x) {
    return __builtin_amdgcn_rcpf(1.f + __builtin_amdgcn_exp2f(-LOG2E * x));
}
__device__ __forceinline__ float tanh_fast(float x) {
    float e = __builtin_amdgcn_exp2f(-2.f * LOG2E * x);
    return __builtin_amdgcn_rcpf(1.f + e) * 2.f - 1.f;
}
__device__ __forceinline__ f32x4 mfma16(bf16x8 a, bf16x8 b, f32x4 c) {
    return __builtin_amdgcn_mfma_f32_16x16x32_bf16(a, b, c, 0, 0, 0);
}
__device__ __forceinline__ bf16x8 cvt8(float4 a, float4 b) {
    bf16x8 f;
    f[0] = (__bf16)a.x; f[1] = (__bf16)a.y; f[2] = (__bf16)a.z; f[3] = (__bf16)a.w;
    f[4] = (__bf16)b.x; f[5] = (__bf16)b.y; f[6] = (__bf16)b.z; f[7] = (__bf16)b.w;
    return f;
}
__device__ __forceinline__ bf16x8 cvt8s(float4 a, float4 b, float s) {
    bf16x8 f;
    f[0] = (__bf16)(a.x*s); f[1] = (__bf16)(a.y*s); f[2] = (__bf16)(a.z*s); f[3] = (__bf16)(a.w*s);
    f[4] = (__bf16)(b.x*s); f[5] = (__bf16)(b.y*s); f[6] = (__bf16)(b.z*s); f[7] = (__bf16)(b.w*s);
    return f;
}
__device__ __forceinline__ bf16x4 cvt4(float4 a) {
    bf16x4 f;
    f[0] = (__bf16)a.x; f[1] = (__bf16)a.y; f[2] = (__bf16)a.z; f[3] = (__bf16)a.w;
    return f;
}
__device__ __forceinline__ float bflo(unsigned u) { return __uint_as_float(u << 16); }
__device__ __forceinline__ float bfhi(unsigned u) { return __uint_as_float(u & 0xffff0000u); }

// ===========================================================================
// FAST PATH
// ===========================================================================

// ---- fold: Wcbf = bf16(scale * (W_ih @ lin_W)), bcA = scale*(W_ih@lin_b + b_ih)
__global__ void fold_bf16_kernel(const float* __restrict__ lin_W,
                                 const float* __restrict__ lin_b,
                                 const float* __restrict__ W_ih,
                                 const float* __restrict__ b_ih,
                                 __bf16* __restrict__ Wcbf,
                                 float* __restrict__ bcA) {
    const int g = blockIdx.x;
    const int d = threadIdx.x;
    const float sc = (g < 2 * HID) ? SC_RZ : SC_N;
    float acc = 0.f;
    #pragma unroll 16
    for (int e = 0; e < HID; ++e) acc += W_ih[g * HID + e] * lin_W[e * HID + d];
    Wcbf[g * HID + d] = (__bf16)(acc * sc);
    if (d == 0) {
        float b = 0.f;
        for (int e = 0; e < HID; ++e) b += W_ih[g * HID + e] * lin_b[e];
        bcA[g] = (b + b_ih[g]) * sc;
    }
}

// ---- gx GEMM: 1024 blocks x 512 thr (8 waves). Block: 128 m-rows.
// Wave w owns g-tiles w*3..w*3+2 (A resident, 48 VGPR). Stores repacked
// through LDS -> perfectly coalesced 3x16B per thread.
__global__ __launch_bounds__(512, 1)
void gemm_gx3(const float* __restrict__ X,
              const __bf16* __restrict__ Wcbf,
              const float* __restrict__ bcA,
              __bf16* __restrict__ gx) {
    const int t   = threadIdx.x;
    const int w   = t >> 6;     // 0..7
    const int l   = t & 63;
    const int col = l & 15;
    const int lr  = l >> 4;
    const int m0  = blockIdx.x * 128;

    __shared__ __align__(16) unsigned char lds[32 * 784];   // 25088 B

    bf16x8 A[3][4];
    #pragma unroll
    for (int j = 0; j < 3; ++j)
        #pragma unroll
        for (int kt = 0; kt < 4; ++kt)
            A[j][kt] = *(const bf16x8*)(Wcbf +
                (size_t)((w * 3 + j) * 16 + col) * HID + kt * 32 + lr * 8);
    #pragma unroll
    for (int j = 0; j < 3; ++j)
        #pragma unroll
        for (int kt = 0; kt < 4; ++kt)
            asm volatile("" : "+v"(A[j][kt]));

    f32x4 vb[3];
    #pragma unroll
    for (int j = 0; j < 3; ++j)
        vb[j] = *(const f32x4*)(bcA + (w * 3 + j) * 16 + lr * 4);

    const int smr = t >> 4;   // 0..31: local m-row for store phase
    const int sck = t & 15;   // 48B chunk

    for (int p = 0; p < 4; ++p) {   // pairs of 16-row m-tiles
        #pragma unroll
        for (int sub = 0; sub < 2; ++sub) {
            const int mt = p * 2 + sub;
            const int m_ = m0 + mt * 16 + col;
            bf16x8 Bx[4];
            const float* px = X + (size_t)m_ * HID + lr * 8;
            #pragma unroll
            for (int kt = 0; kt < 4; ++kt)
                Bx[kt] = cvt8(*(const float4*)(px + kt * 32),
                              *(const float4*)(px + kt * 32 + 4));
            #pragma unroll
            for (int j = 0; j < 3; ++j) {
                f32x4 acc = vb[j];
                acc = mfma16(A[j][0], Bx[0], acc);
                acc = mfma16(A[j][1], Bx[1], acc);
                acc = mfma16(A[j][2], Bx[2], acc);
                acc = mfma16(A[j][3], Bx[3], acc);
                float4 o; o.x = acc[0]; o.y = acc[1]; o.z = acc[2]; o.w = acc[3];
                *(bf16x4*)(lds + (sub * 16 + col) * 784 +
                           ((w * 3 + j) * 16 + lr * 4) * 2) = cvt4(o);
            }
        }
        __syncthreads();
        {
            const int m_ = m0 + p * 32 + smr;
            const unsigned char* src = lds + smr * 784 + sck * 48;
            char* dst = (char*)gx + (size_t)m_ * (G3 * 2) + sck * 48;
            *(float4*)(dst)      = *(const float4*)(src);
            *(float4*)(dst + 16) = *(const float4*)(src + 16);
            *(float4*)(dst + 32) = *(const float4*)(src + 32);
        }
        __syncthreads();
    }
}

// ---- light scan: hazard fence at step TOP; whole body = one sched region --
#define SCAN_STEP(S, HR, HW, CR, CZ, CN, NR, NZ, NN)                          \
  {                                                                           \
    /* 1. issue gx[S+1] prefetch via raw asm (cannot be sunk) */              \
    int sp_ = (S) + 1; if (sp_ > SEQ - 1) sp_ = SEQ - 1;                      \
    const __bf16* p_ = gx + (size_t)sp_ * (BATCH * G3) + gxoff;               \
    asm volatile("global_load_dwordx2 %0, %3, off\n\t"                        \
                 "global_load_dwordx2 %1, %3, off offset:256\n\t"             \
                 "global_load_dwordx2 %2, %3, off offset:512"                 \
                 : "=&v"(NR), "=&v"(NZ), "=&v"(NN) : "v"(p_) : "memory");     \
    /* 2. counted wait AT TOP: newest 4 = this step's 3 loads + ~1 store;     \
          guarantees last step's loads (this step's gx) landed. SB(0)         \
          fences reg-only uses (rule #18) while leaving the whole body        \
          below as ONE scheduling region for MFMA/trans overlap. */           \
    asm volatile("s_waitcnt vmcnt(4)" ::: "memory");                          \
    __builtin_amdgcn_sched_barrier(0);                                        \
    /* 3. h B-fragments from LDS */                                           \
    bf16x8 Bh_[4];                                                            \
    _Pragma("unroll")                                                         \
    for (int kt = 0; kt < 4; ++kt)                                            \
        Bh_[kt] = *(const bf16x8*)((HR) + SW(col, kt * 64 + lr * 16));        \
    /* 4. MFMA grouped by gate so ar finishes first -> r-sigm overlaps */     \
    f32x4 ar_ = vbr, az_ = vbz, anh_ = vbnh;                                  \
    _Pragma("unroll")                                                         \
    for (int kt = 0; kt < 4; ++kt) ar_  = mfma16(aW[0][kt], Bh_[kt], ar_);    \
    _Pragma("unroll")                                                         \
    for (int kt = 0; kt < 4; ++kt) az_  = mfma16(aW[1][kt], Bh_[kt], az_);    \
    _Pragma("unroll")                                                         \
    for (int kt = 0; kt < 4; ++kt) anh_ = mfma16(aW[2][kt], Bh_[kt], anh_);   \
    /* 5. gate math: scales pre-folded, pure exp2/rcp forms */                \
    float xr_[4] = { bflo(CR.x), bfhi(CR.x), bflo(CR.y), bfhi(CR.y) };        \
    float xz_[4] = { bflo(CZ.x), bfhi(CZ.x), bflo(CZ.y), bfhi(CZ.y) };        \
    float xn_[4] = { bflo(CN.x), bfhi(CN.x), bflo(CN.y), bfhi(CN.y) };        \
    f32x4 hnew_;                                                              \
    _Pragma("unroll")                                                         \
    for (int q = 0; q < 4; ++q) {                                             \
        float r_ = __builtin_amdgcn_rcpf(1.f + __builtin_amdgcn_exp2f(ar_[q] + xr_[q])); \
        float z_ = __builtin_amdgcn_rcpf(1.f + __builtin_amdgcn_exp2f(az_[q] + xz_[q])); \
        float n_ = 2.f * __builtin_amdgcn_rcpf(1.f + __builtin_amdgcn_exp2f(xn_[q] + r_ * anh_[q])) - 1.f; \
        hnew_[q] = n_ + z_ * (hold[q] - n_);                                  \
    }                                                                         \
    hold = hnew_;                                                             \
    *(bf16x4*)((HW) + SW(col, (w * 16 + lr * 4) * 2)) = cvt4(*(float4*)&hnew_); \
    float4 o_; o_.x = hnew_[0]; o_.y = hnew_[1]; o_.z = hnew_[2]; o_.w = hnew_[3]; \
    *(float4*)(out + ((size_t)(S) * BATCH + bb + col) * HID + w * 16 + lr * 4) = o_; \
    /* 6. single barrier: LDS visibility only; vmcnt flows across */          \
    asm volatile("s_waitcnt lgkmcnt(0)" ::: "memory");                        \
    __builtin_amdgcn_s_barrier();                                             \
  }

__global__ __launch_bounds__(512, 2)
void gru_scan_light3(const float* __restrict__ h0,
                     const float* __restrict__ W_hh,
                     const float* __restrict__ b_hh,
                     const __bf16* __restrict__ gx,
                     float* __restrict__ out) {
    const int t   = threadIdx.x;
    const int w   = t >> 6;     // 0..7: row tile
    const int l   = t & 63;
    const int col = l & 15;
    const int lr  = l >> 4;
    const int bb  = blockIdx.x * NB;

    __shared__ __align__(16) unsigned char lds[8192];
    unsigned char* hA = lds;
    unsigned char* hB = lds + 4096;

    auto SW = [](int b, int off) { return b * 256 + (off ^ ((b & 7) << 4)); };

    // resident W_hh A-fragments (48 VGPR), pre-scaled per gate, pinned
    bf16x8 aW[3][4];
    #pragma unroll
    for (int g3 = 0; g3 < 3; ++g3) {
        const float s = (g3 < 2) ? SC_RZ : SC_N;
        #pragma unroll
        for (int kt = 0; kt < 4; ++kt) {
            const int row = g3 * HID + w * 16 + col;
            const float* pw = W_hh + row * HID + kt * 32 + lr * 8;
            aW[g3][kt] = cvt8s(*(const float4*)pw, *(const float4*)(pw + 4), s);
        }
    }
    #pragma unroll
    for (int g3 = 0; g3 < 3; ++g3)
        #pragma unroll
        for (int kt = 0; kt < 4; ++kt)
            asm volatile("" : "+v"(aW[g3][kt]));

    f32x4 vbr, vbz, vbnh;
    #pragma unroll
    for (int q = 0; q < 4; ++q) {
        const int g = w * 16 + lr * 4 + q;
        vbr[q]  = b_hh[g] * SC_RZ;
        vbz[q]  = b_hh[HID + g] * SC_RZ;
        vbnh[q] = b_hh[2 * HID + g] * SC_N;
    }

    f32x4 hold = *(const f32x4*)(h0 + (size_t)(bb + col) * HID + w * 16 + lr * 4);

    // force all compiler vmem to complete in the prologue (vmcnt accounting)
    asm volatile("" :: "v"(hold), "v"(vbr), "v"(vbz), "v"(vbnh));

    const size_t gxoff = (size_t)(bb + col) * G3 + w * 16 + lr * 4;

    if (t < 256) {
        const int hb = t >> 4, hk = (t & 15) * 8;
        const float* ph = h0 + (size_t)(bb + hb) * HID + hk;
        *(bf16x8*)(hA + SW(hb, hk * 2)) =
            cvt8(*(const float4*)ph, *(const float4*)(ph + 4));
    }

    // prime: gx[0] via asm (3 loads) + 1 dummy load (uniform vmcnt math)
    uint2 gcr, gcz, gcn, gnr, gnz, gnn, gdm;
    {
        const __bf16* p_ = gx + gxoff;
        asm volatile("global_load_dwordx2 %0, %3, off\n\t"
                     "global_load_dwordx2 %1, %3, off offset:256\n\t"
                     "global_load_dwordx2 %2, %3, off offset:512"
                     : "=&v"(gcr), "=&v"(gcz), "=&v"(gcn) : "v"(p_) : "memory");
        asm volatile("global_load_dwordx2 %0, %1, off"
                     : "=&v"(gdm) : "v"(p_) : "memory");
    }
    asm volatile("s_waitcnt lgkmcnt(0)" ::: "memory");
    __builtin_amdgcn_s_barrier();

    for (int s0 = 0; s0 < SEQ; s0 += 2) {
        SCAN_STEP(s0,     hA, hB, gcr, gcz, gcn, gnr, gnz, gnn);
        SCAN_STEP(s0 + 1, hB, hA, gnr, gnz, gnn, gcr, gcz, gcn);
    }
    asm volatile("" :: "v"(gdm));
}

// ===========================================================================
// FALLBACK PATH (round-7 kernels, ~439 us) -- used when ws_size is small
// ===========================================================================
__global__ void fold_kernel(const float* __restrict__ lin_W,
                            const float* __restrict__ lin_b,
                            const float* __restrict__ W_ih,
                            const float* __restrict__ b_ih,
                            float* __restrict__ Wc,
                            float* __restrict__ bcA) {
    const int g = blockIdx.x;
    const int d = threadIdx.x;
    float acc = 0.f;
    for (int e = 0; e < HID; ++e) acc += W_ih[g * HID + e] * lin_W[e * HID + d];
    Wc[g * HID + d] = acc;
    if (d == 0) {
        float b = 0.f;
        for (int e = 0; e < HID; ++e) b += W_ih[g * HID + e] * lin_b[e];
        bcA[g] = b + b_ih[g];
    }
}

__global__ __launch_bounds__(512, 2)
void gru_scan_mfma(const float* __restrict__ X,
                   const float* __restrict__ h0,
                   const float* __restrict__ W_hh,
                   const float* __restrict__ b_hh,
                   const float* __restrict__ Wc,
                   const float* __restrict__ bcA,
                   float* __restrict__ out) {
    const int t   = threadIdx.x;
    const int w   = t >> 6;
    const int l   = t & 63;
    const int col = l & 15;
    const int lr  = l >> 4;
    const int bb  = blockIdx.x * NB;

    __shared__ __align__(16) unsigned char lds[16384];
    unsigned char* hA = lds;
    unsigned char* hB = lds + 4096;
    unsigned char* xA = lds + 8192;
    unsigned char* xB = lds + 12288;

    auto SW = [](int b, int off) { return b * 256 + (off ^ ((b & 7) << 4)); };

    bf16x8 aW[3][4], aC[3][4];
    #pragma unroll
    for (int g3 = 0; g3 < 3; ++g3)
        #pragma unroll
        for (int kt = 0; kt < 4; ++kt) {
            const int row = g3 * HID + w * 16 + col;
            const float* pw = W_hh + row * HID + kt * 32 + lr * 8;
            const float* pc = Wc   + row * HID + kt * 32 + lr * 8;
            aW[g3][kt] = cvt8(*(const float4*)pw, *(const float4*)(pw + 4));
            aC[g3][kt] = cvt8(*(const float4*)pc, *(const float4*)(pc + 4));
        }
    #pragma unroll
    for (int g3 = 0; g3 < 3; ++g3)
        #pragma unroll
        for (int kt = 0; kt < 4; ++kt) {
            asm volatile("" : "+v"(aW[g3][kt]));
            asm volatile("" : "+v"(aC[g3][kt]));
        }

    f32x4 vbr, vbz, vbnx, vbnh;
    #pragma unroll
    for (int q = 0; q < 4; ++q) {
        const int g = w * 16 + lr * 4 + q;
        vbr[q]  = bcA[g] + b_hh[g];
        vbz[q]  = bcA[HID + g] + b_hh[HID + g];
        vbnx[q] = bcA[2 * HID + g];
        vbnh[q] = b_hh[2 * HID + g];
    }

    f32x4 hold = *(const f32x4*)(h0 + (size_t)(bb + col) * HID + w * 16 + lr * 4);

    const int sb = t >> 5;
    const int sk = (t & 31) * 4;

    float4 xp, xq;
    if (t < 256) {
        const int hb = t >> 4, hk = (t & 15) * 8;
        const float* ph = h0 + (size_t)(bb + hb) * HID + hk;
        *(bf16x8*)(hA + SW(hb, hk * 2)) =
            cvt8(*(const float4*)ph, *(const float4*)(ph + 4));
    }
    {
        const float* px = X + ((size_t)0 * BATCH + bb + sb) * HID + sk;
        *(bf16x4*)(xA + SW(sb, sk * 2)) = cvt4(*(const float4*)px);
        const float* p1 = X + ((size_t)1 * BATCH + bb + sb) * HID + sk;
        xp = *(const float4*)p1;
    }
    asm volatile("s_waitcnt lgkmcnt(0)" ::: "memory");
    __builtin_amdgcn_s_barrier();

    auto STEP = [&](int s, unsigned char* hR, unsigned char* hW,
                    unsigned char* xR, unsigned char* xW,
                    float4& xc, float4& xn) {
        *(bf16x4*)(xW + SW(sb, sk * 2)) = cvt4(xc);
        {
            int sp = s + 2; if (sp > SEQ - 1) sp = SEQ - 1;
            const float* px = X + ((size_t)sp * BATCH + bb + sb) * HID + sk;
            xn = *(const float4*)px;
        }
        bf16x8 Bh[4], Bx[4];
        #pragma unroll
        for (int kt = 0; kt < 4; ++kt) {
            Bh[kt] = *(const bf16x8*)(hR + SW(col, kt * 64 + lr * 16));
            Bx[kt] = *(const bf16x8*)(xR + SW(col, kt * 64 + lr * 16));
        }
        f32x4 ar = vbr, az = vbz, anh = vbnh, anx = vbnx;
        #pragma unroll
        for (int kt = 0; kt < 4; ++kt) {
            ar  = mfma16(aW[0][kt], Bh[kt], ar);
            ar  = mfma16(aC[0][kt], Bx[kt], ar);
            az  = mfma16(aW[1][kt], Bh[kt], az);
            az  = mfma16(aC[1][kt], Bx[kt], az);
            anh = mfma16(aW[2][kt], Bh[kt], anh);
            anx = mfma16(aC[2][kt], Bx[kt], anx);
        }
        f32x4 hnew;
        #pragma unroll
        for (int q = 0; q < 4; ++q) {
            float r = sigm(ar[q]);
            float z = sigm(az[q]);
            float n = tanh_fast(anx[q] + r * anh[q]);
            hnew[q] = n + z * (hold[q] - n);
        }
        hold = hnew;
        *(bf16x4*)(hW + SW(col, (w * 16 + lr * 4) * 2)) = cvt4(*(float4*)&hnew);
        float4 o; o.x = hnew[0]; o.y = hnew[1]; o.z = hnew[2]; o.w = hnew[3];
        *(float4*)(out + ((size_t)s * BATCH + bb + col) * HID + w * 16 + lr * 4) = o;
        asm volatile("s_waitcnt lgkmcnt(0)" ::: "memory");
        __builtin_amdgcn_s_barrier();
    };

    for (int s0 = 0; s0 < SEQ; s0 += 2) {
        STEP(s0,     hA, hB, xA, xB, xp, xq);
        STEP(s0 + 1, hB, hA, xB, xA, xq, xp);
    }
}

// ---------------------------------------------------------------------------
extern "C" void kernel_launch(void* const* d_in, const int* in_sizes, int n_in,
                              void* d_out, int out_size, void* d_ws, size_t ws_size,
                              hipStream_t stream) {
    const float* X     = (const float*)d_in[0];
    const float* h0    = (const float*)d_in[1];
    const float* lin_W = (const float*)d_in[2];
    const float* lin_b = (const float*)d_in[3];
    const float* W_ih  = (const float*)d_in[4];
    const float* W_hh  = (const float*)d_in[5];
    const float* b_ih  = (const float*)d_in[6];
    const float* b_hh  = (const float*)d_in[7];
    float* out = (float*)d_out;

    const size_t GX_BYTES   = (size_t)SEQ * BATCH * G3 * 2;  // 100663296
    const size_t WCBF_BYTES = (size_t)G3 * HID * 2;          // 98304
    const size_t BCA_BYTES  = (size_t)G3 * 4;                // 1536

    if (ws_size >= GX_BYTES + WCBF_BYTES + BCA_BYTES) {
        __bf16* gxp  = (__bf16*)d_ws;
        __bf16* Wcbf = (__bf16*)((char*)d_ws + GX_BYTES);
        float*  bcA  = (float*)((char*)d_ws + GX_BYTES + WCBF_BYTES);

        fold_bf16_kernel<<<G3, HID, 0, stream>>>(lin_W, lin_b, W_ih, b_ih, Wcbf, bcA);
        gemm_gx3<<<(SEQ * BATCH) / 128, 512, 0, stream>>>(X, Wcbf, bcA, gxp);
        gru_scan_light3<<<NBLK, 512, 0, stream>>>(h0, W_hh, b_hh, gxp, out);
    } else {
        float* Wc  = (float*)d_ws;
        float* bcA = Wc + G3 * HID;
        fold_kernel<<<G3, HID, 0, stream>>>(lin_W, lin_b, W_ih, b_ih, Wc, bcA);
        gru_scan_mfma<<<NBLK, 512, 0, stream>>>(X, h0, W_hh, b_hh, Wc, bcA, out);
    }
}

// Round 11
// 363.665 us; speedup vs baseline: 1.3334x; 1.3334x over previous
//
#include <hip/hip_runtime.h>
#include <math.h>

#define HID 128
#define G3  384
#define BATCH 256
#define SEQ 512
#define NB 16            // batch tile (fallback scan)
#define NBLK (BATCH/NB)
#define NB4 4            // batch tile (split scan)
#define NBLK4 (BATCH/NB4)

typedef __bf16 bf16x8 __attribute__((ext_vector_type(8)));
typedef __bf16 bf16x4 __attribute__((ext_vector_type(4)));
typedef float  f32x4  __attribute__((ext_vector_type(4)));

#define LOG2E 1.44269504088896f
// gate scales folded into weights/biases: r,z: -log2e ; n: -2*log2e
#define SC_RZ (-1.44269504088896f)
#define SC_N  (-2.88539008177793f)

__device__ __forceinline__ float sigm(float x) {
    return __builtin_amdgcn_rcpf(1.f + __builtin_amdgcn_exp2f(-LOG2E * x));
}
__device__ __forceinline__ float tanh_fast(float x) {
    float e = __builtin_amdgcn_exp2f(-2.f * LOG2E * x);
    return __builtin_amdgcn_rcpf(1.f + e) * 2.f - 1.f;
}
__device__ __forceinline__ f32x4 mfma16(bf16x8 a, bf16x8 b, f32x4 c) {
    return __builtin_amdgcn_mfma_f32_16x16x32_bf16(a, b, c, 0, 0, 0);
}
__device__ __forceinline__ bf16x8 cvt8(float4 a, float4 b) {
    bf16x8 f;
    f[0] = (__bf16)a.x; f[1] = (__bf16)a.y; f[2] = (__bf16)a.z; f[3] = (__bf16)a.w;
    f[4] = (__bf16)b.x; f[5] = (__bf16)b.y; f[6] = (__bf16)b.z; f[7] = (__bf16)b.w;
    return f;
}
__device__ __forceinline__ bf16x8 cvt8s(float4 a, float4 b, float s) {
    bf16x8 f;
    f[0] = (__bf16)(a.x*s); f[1] = (__bf16)(a.y*s); f[2] = (__bf16)(a.z*s); f[3] = (__bf16)(a.w*s);
    f[4] = (__bf16)(b.x*s); f[5] = (__bf16)(b.y*s); f[6] = (__bf16)(b.z*s); f[7] = (__bf16)(b.w*s);
    return f;
}
__device__ __forceinline__ bf16x4 cvt4(float4 a) {
    bf16x4 f;
    f[0] = (__bf16)a.x; f[1] = (__bf16)a.y; f[2] = (__bf16)a.z; f[3] = (__bf16)a.w;
    return f;
}

// ===========================================================================
// FAST PATH
// ===========================================================================

// ---- fold: Wcbf = bf16(scale*(W_ih@lin_W)), bcA = scale*(W_ih@lin_b+b_ih)
__global__ void fold_bf16_kernel(const float* __restrict__ lin_W,
                                 const float* __restrict__ lin_b,
                                 const float* __restrict__ W_ih,
                                 const float* __restrict__ b_ih,
                                 __bf16* __restrict__ Wcbf,
                                 float* __restrict__ bcA) {
    const int g = blockIdx.x;
    const int d = threadIdx.x;
    const float sc = (g < 2 * HID) ? SC_RZ : SC_N;
    float acc = 0.f;
    #pragma unroll 16
    for (int e = 0; e < HID; ++e) acc += W_ih[g * HID + e] * lin_W[e * HID + d];
    Wcbf[g * HID + d] = (__bf16)(acc * sc);
    if (d == 0) {
        float b = 0.f;
        for (int e = 0; e < HID; ++e) b += W_ih[g * HID + e] * lin_b[e];
        bcA[g] = (b + b_ih[g]) * sc;
    }
}

// ---- gx GEMM (round-9 version, measured fastest aux): resident A,
// streamed X, 1024 blocks x 256 thr ----------------------------------------
#define GEMM_TILE(MT, CUR, NXT)                                               \
  {                                                                           \
    int mtn_ = (MT) + 1; if (mtn_ > 7) mtn_ = 7;                              \
    const float* pxn_ = X + (size_t)(m0 + mtn_ * 16 + col) * HID + lr * 8;    \
    _Pragma("unroll")                                                         \
    for (int kt = 0; kt < 4; ++kt) {                                          \
        NXT[2 * kt]     = *(const float4*)(pxn_ + kt * 32);                   \
        NXT[2 * kt + 1] = *(const float4*)(pxn_ + kt * 32 + 4);               \
    }                                                                         \
    bf16x8 Bx_[4];                                                            \
    _Pragma("unroll")                                                         \
    for (int kt = 0; kt < 4; ++kt) Bx_[kt] = cvt8(CUR[2 * kt], CUR[2 * kt + 1]); \
    const int m_ = m0 + (MT) * 16 + col;                                      \
    _Pragma("unroll")                                                         \
    for (int j = 0; j < 6; ++j) {                                             \
        f32x4 acc_ = vb[j];                                                   \
        acc_ = mfma16(A[j][0], Bx_[0], acc_);                                 \
        acc_ = mfma16(A[j][1], Bx_[1], acc_);                                 \
        acc_ = mfma16(A[j][2], Bx_[2], acc_);                                 \
        acc_ = mfma16(A[j][3], Bx_[3], acc_);                                 \
        float4 o_; o_.x = acc_[0]; o_.y = acc_[1]; o_.z = acc_[2]; o_.w = acc_[3]; \
        *(bf16x4*)(gx + (size_t)m_ * G3 + (w * 6 + j) * 16 + lr * 4) = cvt4(o_); \
    }                                                                         \
  }

__global__ __launch_bounds__(256, 2)
void gemm_gx2(const float* __restrict__ X,
              const __bf16* __restrict__ Wcbf,
              const float* __restrict__ bcA,
              __bf16* __restrict__ gx) {
    const int t   = threadIdx.x;
    const int w   = t >> 6;
    const int l   = t & 63;
    const int col = l & 15;
    const int lr  = l >> 4;
    const int m0  = blockIdx.x * 128;

    bf16x8 A[6][4];
    #pragma unroll
    for (int j = 0; j < 6; ++j)
        #pragma unroll
        for (int kt = 0; kt < 4; ++kt)
            A[j][kt] = *(const bf16x8*)(Wcbf +
                (size_t)((w * 6 + j) * 16 + col) * HID + kt * 32 + lr * 8);
    #pragma unroll
    for (int j = 0; j < 6; ++j)
        #pragma unroll
        for (int kt = 0; kt < 4; ++kt)
            asm volatile("" : "+v"(A[j][kt]));

    f32x4 vb[6];
    #pragma unroll
    for (int j = 0; j < 6; ++j)
        vb[j] = *(const f32x4*)(bcA + (w * 6 + j) * 16 + lr * 4);

    float4 xe[8], xo[8];
    {
        const float* px = X + (size_t)(m0 + col) * HID + lr * 8;
        #pragma unroll
        for (int kt = 0; kt < 4; ++kt) {
            xe[2 * kt]     = *(const float4*)(px + kt * 32);
            xe[2 * kt + 1] = *(const float4*)(px + kt * 32 + 4);
        }
    }
    for (int mt = 0; mt < 8; mt += 2) {
        GEMM_TILE(mt,     xe, xo);
        GEMM_TILE(mt + 1, xo, xe);
    }
}

// ---- split scan: NB4=4 batch/block, 64 blocks. Phase 1 = MFMA (gh -> LDS),
// Phase 2 = 1 h-element per thread -> 6 trans instr/wave/step (was 24). ----
#define SPLIT_STEP(S, C0, C1, C2, N0, N1, N2)                                 \
  {                                                                           \
    /* phase 1: gh = scaled W_hh @ h (+scaled b_hh via acc init) */           \
    bf16x8 Bh_[4];                                                            \
    _Pragma("unroll")                                                         \
    for (int kt = 0; kt < 4; ++kt)                                            \
        Bh_[kt] = *(const bf16x8*)(hbuf + SW(col, kt * 64 + lr * 16));        \
    f32x4 ar_ = vbr, az_ = vbz, anh_ = vbnh;                                  \
    _Pragma("unroll")                                                         \
    for (int kt = 0; kt < 4; ++kt) {                                          \
        ar_  = mfma16(aW[0][kt], Bh_[kt], ar_);                               \
        az_  = mfma16(aW[1][kt], Bh_[kt], az_);                               \
        anh_ = mfma16(aW[2][kt], Bh_[kt], anh_);                              \
    }                                                                         \
    if (col < NB4) {                                                          \
        float* gp_ = ghsF + col * 388 + w * 16 + lr * 4;                      \
        *(f32x4*)(gp_)       = ar_;                                           \
        *(f32x4*)(gp_ + 128) = az_;                                           \
        *(f32x4*)(gp_ + 256) = anh_;                                          \
    }                                                                         \
    asm volatile("s_waitcnt lgkmcnt(0)" ::: "memory");                        \
    __builtin_amdgcn_s_barrier();                                             \
    /* phase 2: issue gx[S+1] prefetch (asm, cannot sink) */                  \
    int sp_ = (S) + 1; if (sp_ > SEQ - 1) sp_ = SEQ - 1;                      \
    const __bf16* p_ = gx + (size_t)sp_ * (BATCH * G3) + gxoff;               \
    asm volatile("global_load_ushort %0, %3, off\n\t"                         \
                 "global_load_ushort %1, %3, off offset:256\n\t"              \
                 "global_load_ushort %2, %3, off offset:512"                  \
                 : "=&v"(N0), "=&v"(N1), "=&v"(N2) : "v"(p_) : "memory");     \
    float gr_ = ghsF[bi * 388 + ri];                                          \
    float gz_ = ghsF[bi * 388 + 128 + ri];                                    \
    float gn_ = ghsF[bi * 388 + 256 + ri];                                    \
    /* counted wait: FIFO order ... L(S)x3, store(S-1), L(S+1)x3 |wait|      \
       -> vmcnt(4) guarantees L(S) landed */                                  \
    asm volatile("s_waitcnt vmcnt(4)" ::: "memory");                          \
    __builtin_amdgcn_sched_barrier(0);                                        \
    float xr_ = __uint_as_float((C0) << 16);                                  \
    float xz_ = __uint_as_float((C1) << 16);                                  \
    float xn_ = __uint_as_float((C2) << 16);                                  \
    float r_ = __builtin_amdgcn_rcpf(1.f + __builtin_amdgcn_exp2f(gr_ + xr_));\
    float z_ = __builtin_amdgcn_rcpf(1.f + __builtin_amdgcn_exp2f(gz_ + xz_));\
    float n_ = 2.f * __builtin_amdgcn_rcpf(1.f + __builtin_amdgcn_exp2f(xn_ + r_ * gn_)) - 1.f; \
    float hn_ = n_ + z_ * (hold - n_);                                        \
    hold = hn_;                                                               \
    *(__bf16*)(hbuf + SW(bi, ri * 2)) = (__bf16)hn_;                          \
    out[((size_t)(S) * BATCH + bb + bi) * HID + ri] = hn_;                    \
    asm volatile("s_waitcnt lgkmcnt(0)" ::: "memory");                        \
    __builtin_amdgcn_s_barrier();                                             \
  }

__global__ __launch_bounds__(512, 2)
void gru_scan_split(const float* __restrict__ h0,
                    const float* __restrict__ W_hh,
                    const float* __restrict__ b_hh,
                    const __bf16* __restrict__ gx,
                    float* __restrict__ out) {
    const int t   = threadIdx.x;
    const int w   = t >> 6;     // 0..7: row tile (16 rows/gate)
    const int l   = t & 63;
    const int col = l & 15;
    const int lr  = l >> 4;
    const int bb  = blockIdx.x * NB4;
    const int bi  = t >> 7;     // 0..3: batch elem (phase 2)
    const int ri  = t & 127;    // hidden row     (phase 2)

    __shared__ __align__(16) unsigned char lds[4096 + 4 * 388 * 4];
    unsigned char* hbuf = lds;                    // [16][128] bf16, swizzled
    float* ghsF = (float*)(lds + 4096);           // [4][388] f32 gh scratch

    auto SW = [](int b, int off) { return b * 256 + (off ^ ((b & 7) << 4)); };

    // resident W_hh A-fragments (48 VGPR), pre-scaled per gate, pinned
    bf16x8 aW[3][4];
    #pragma unroll
    for (int g3 = 0; g3 < 3; ++g3) {
        const float s = (g3 < 2) ? SC_RZ : SC_N;
        #pragma unroll
        for (int kt = 0; kt < 4; ++kt) {
            const int row = g3 * HID + w * 16 + col;
            const float* pw = W_hh + row * HID + kt * 32 + lr * 8;
            aW[g3][kt] = cvt8s(*(const float4*)pw, *(const float4*)(pw + 4), s);
        }
    }
    #pragma unroll
    for (int g3 = 0; g3 < 3; ++g3)
        #pragma unroll
        for (int kt = 0; kt < 4; ++kt)
            asm volatile("" : "+v"(aW[g3][kt]));

    // scaled b_hh as acc initializers (rows w*16 + lr*4 + q)
    f32x4 vbr, vbz, vbnh;
    #pragma unroll
    for (int q = 0; q < 4; ++q) {
        const int g = w * 16 + lr * 4 + q;
        vbr[q]  = b_hh[g] * SC_RZ;
        vbz[q]  = b_hh[HID + g] * SC_RZ;
        vbnh[q] = b_hh[2 * HID + g] * SC_N;
    }

    // per-thread h state (phase-2 element)
    float hold = h0[(size_t)(bb + bi) * HID + ri];
    asm volatile("" :: "v"(hold), "v"(vbr), "v"(vbz), "v"(vbnh));

    const size_t gxoff = (size_t)(bb + bi) * G3 + ri;

    // stage h0 rows 0..3 (t<64) and zero rows 4..15 (t=64..255)
    if (t < 64) {
        const int sb = t >> 4, k8 = (t & 15) * 8;
        const float* ph = h0 + (size_t)(bb + sb) * HID + k8;
        *(bf16x8*)(hbuf + SW(sb, k8 * 2)) =
            cvt8(*(const float4*)ph, *(const float4*)(ph + 4));
    } else if (t < 256) {
        const int sb = t >> 4, k8 = (t & 15) * 8;
        uint4 z = {0u, 0u, 0u, 0u};
        *(uint4*)(hbuf + SW(sb, k8 * 2)) = z;
    }

    // prime: gx[0] (3 ushort asm loads) + 1 dummy (uniform vmcnt math)
    unsigned c0, c1, c2, n0, n1, n2, dm;
    {
        const __bf16* p_ = gx + gxoff;
        asm volatile("global_load_ushort %0, %3, off\n\t"
                     "global_load_ushort %1, %3, off offset:256\n\t"
                     "global_load_ushort %2, %3, off offset:512"
                     : "=&v"(c0), "=&v"(c1), "=&v"(c2) : "v"(p_) : "memory");
        asm volatile("global_load_ushort %0, %1, off"
                     : "=&v"(dm) : "v"(p_) : "memory");
    }
    asm volatile("s_waitcnt lgkmcnt(0)" ::: "memory");
    __builtin_amdgcn_s_barrier();

    for (int s0 = 0; s0 < SEQ; s0 += 2) {
        SPLIT_STEP(s0,     c0, c1, c2, n0, n1, n2);
        SPLIT_STEP(s0 + 1, n0, n1, n2, c0, c1, c2);
    }
    asm volatile("" :: "v"(dm));
}

// ===========================================================================
// FALLBACK PATH (round-7 kernels, ~439 us) -- used when ws_size is small
// ===========================================================================
__global__ void fold_kernel(const float* __restrict__ lin_W,
                            const float* __restrict__ lin_b,
                            const float* __restrict__ W_ih,
                            const float* __restrict__ b_ih,
                            float* __restrict__ Wc,
                            float* __restrict__ bcA) {
    const int g = blockIdx.x;
    const int d = threadIdx.x;
    float acc = 0.f;
    for (int e = 0; e < HID; ++e) acc += W_ih[g * HID + e] * lin_W[e * HID + d];
    Wc[g * HID + d] = acc;
    if (d == 0) {
        float b = 0.f;
        for (int e = 0; e < HID; ++e) b += W_ih[g * HID + e] * lin_b[e];
        bcA[g] = b + b_ih[g];
    }
}

__global__ __launch_bounds__(512, 2)
void gru_scan_mfma(const float* __restrict__ X,
                   const float* __restrict__ h0,
                   const float* __restrict__ W_hh,
                   const float* __restrict__ b_hh,
                   const float* __restrict__ Wc,
                   const float* __restrict__ bcA,
                   float* __restrict__ out) {
    const int t   = threadIdx.x;
    const int w   = t >> 6;
    const int l   = t & 63;
    const int col = l & 15;
    const int lr  = l >> 4;
    const int bb  = blockIdx.x * NB;

    __shared__ __align__(16) unsigned char lds[16384];
    unsigned char* hA = lds;
    unsigned char* hB = lds + 4096;
    unsigned char* xA = lds + 8192;
    unsigned char* xB = lds + 12288;

    auto SW = [](int b, int off) { return b * 256 + (off ^ ((b & 7) << 4)); };

    bf16x8 aW[3][4], aC[3][4];
    #pragma unroll
    for (int g3 = 0; g3 < 3; ++g3)
        #pragma unroll
        for (int kt = 0; kt < 4; ++kt) {
            const int row = g3 * HID + w * 16 + col;
            const float* pw = W_hh + row * HID + kt * 32 + lr * 8;
            const float* pc = Wc   + row * HID + kt * 32 + lr * 8;
            aW[g3][kt] = cvt8(*(const float4*)pw, *(const float4*)(pw + 4));
            aC[g3][kt] = cvt8(*(const float4*)pc, *(const float4*)(pc + 4));
        }
    #pragma unroll
    for (int g3 = 0; g3 < 3; ++g3)
        #pragma unroll
        for (int kt = 0; kt < 4; ++kt) {
            asm volatile("" : "+v"(aW[g3][kt]));
            asm volatile("" : "+v"(aC[g3][kt]));
        }

    f32x4 vbr, vbz, vbnx, vbnh;
    #pragma unroll
    for (int q = 0; q < 4; ++q) {
        const int g = w * 16 + lr * 4 + q;
        vbr[q]  = bcA[g] + b_hh[g];
        vbz[q]  = bcA[HID + g] + b_hh[HID + g];
        vbnx[q] = bcA[2 * HID + g];
        vbnh[q] = b_hh[2 * HID + g];
    }

    f32x4 hold = *(const f32x4*)(h0 + (size_t)(bb + col) * HID + w * 16 + lr * 4);

    const int sb = t >> 5;
    const int sk = (t & 31) * 4;

    float4 xp, xq;
    if (t < 256) {
        const int hb = t >> 4, hk = (t & 15) * 8;
        const float* ph = h0 + (size_t)(bb + hb) * HID + hk;
        *(bf16x8*)(hA + SW(hb, hk * 2)) =
            cvt8(*(const float4*)ph, *(const float4*)(ph + 4));
    }
    {
        const float* px = X + ((size_t)0 * BATCH + bb + sb) * HID + sk;
        *(bf16x4*)(xA + SW(sb, sk * 2)) = cvt4(*(const float4*)px);
        const float* p1 = X + ((size_t)1 * BATCH + bb + sb) * HID + sk;
        xp = *(const float4*)p1;
    }
    asm volatile("s_waitcnt lgkmcnt(0)" ::: "memory");
    __builtin_amdgcn_s_barrier();

    auto STEP = [&](int s, unsigned char* hR, unsigned char* hW,
                    unsigned char* xR, unsigned char* xW,
                    float4& xc, float4& xn) {
        *(bf16x4*)(xW + SW(sb, sk * 2)) = cvt4(xc);
        {
            int sp = s + 2; if (sp > SEQ - 1) sp = SEQ - 1;
            const float* px = X + ((size_t)sp * BATCH + bb + sb) * HID + sk;
            xn = *(const float4*)px;
        }
        bf16x8 Bh[4], Bx[4];
        #pragma unroll
        for (int kt = 0; kt < 4; ++kt) {
            Bh[kt] = *(const bf16x8*)(hR + SW(col, kt * 64 + lr * 16));
            Bx[kt] = *(const bf16x8*)(xR + SW(col, kt * 64 + lr * 16));
        }
        f32x4 ar = vbr, az = vbz, anh = vbnh, anx = vbnx;
        #pragma unroll
        for (int kt = 0; kt < 4; ++kt) {
            ar  = mfma16(aW[0][kt], Bh[kt], ar);
            ar  = mfma16(aC[0][kt], Bx[kt], ar);
            az  = mfma16(aW[1][kt], Bh[kt], az);
            az  = mfma16(aC[1][kt], Bx[kt], az);
            anh = mfma16(aW[2][kt], Bh[kt], anh);
            anx = mfma16(aC[2][kt], Bx[kt], anx);
        }
        f32x4 hnew;
        #pragma unroll
        for (int q = 0; q < 4; ++q) {
            float r = sigm(ar[q]);
            float z = sigm(az[q]);
            float n = tanh_fast(anx[q] + r * anh[q]);
            hnew[q] = n + z * (hold[q] - n);
        }
        hold = hnew;
        *(bf16x4*)(hW + SW(col, (w * 16 + lr * 4) * 2)) = cvt4(*(float4*)&hnew);
        float4 o; o.x = hnew[0]; o.y = hnew[1]; o.z = hnew[2]; o.w = hnew[3];
        *(float4*)(out + ((size_t)s * BATCH + bb + col) * HID + w * 16 + lr * 4) = o;
        asm volatile("s_waitcnt lgkmcnt(0)" ::: "memory");
        __builtin_amdgcn_s_barrier();
    };

    for (int s0 = 0; s0 < SEQ; s0 += 2) {
        STEP(s0,     hA, hB, xA, xB, xp, xq);
        STEP(s0 + 1, hB, hA, xB, xA, xq, xp);
    }
}

// ---------------------------------------------------------------------------
extern "C" void kernel_launch(void* const* d_in, const int* in_sizes, int n_in,
                              void* d_out, int out_size, void* d_ws, size_t ws_size,
                              hipStream_t stream) {
    const float* X     = (const float*)d_in[0];
    const float* h0    = (const float*)d_in[1];
    const float* lin_W = (const float*)d_in[2];
    const float* lin_b = (const float*)d_in[3];
    const float* W_ih  = (const float*)d_in[4];
    const float* W_hh  = (const float*)d_in[5];
    const float* b_ih  = (const float*)d_in[6];
    const float* b_hh  = (const float*)d_in[7];
    float* out = (float*)d_out;

    const size_t GX_BYTES   = (size_t)SEQ * BATCH * G3 * 2;  // 100663296
    const size_t WCBF_BYTES = (size_t)G3 * HID * 2;          // 98304
    const size_t BCA_BYTES  = (size_t)G3 * 4;                // 1536

    if (ws_size >= GX_BYTES + WCBF_BYTES + BCA_BYTES) {
        __bf16* gxp  = (__bf16*)d_ws;
        __bf16* Wcbf = (__bf16*)((char*)d_ws + GX_BYTES);
        float*  bcA  = (float*)((char*)d_ws + GX_BYTES + WCBF_BYTES);

        fold_bf16_kernel<<<G3, HID, 0, stream>>>(lin_W, lin_b, W_ih, b_ih, Wcbf, bcA);
        gemm_gx2<<<(SEQ * BATCH) / 128, 256, 0, stream>>>(X, Wcbf, bcA, gxp);
        gru_scan_split<<<NBLK4, 512, 0, stream>>>(h0, W_hh, b_hh, gxp, out);
    } else {
        float* Wc  = (float*)d_ws;
        float* bcA = Wc + G3 * HID;
        fold_kernel<<<G3, HID, 0, stream>>>(lin_W, lin_b, W_ih, b_ih, Wc, bcA);
        gru_scan_mfma<<<NBLK, 512, 0, stream>>>(X, h0, W_hh, b_hh, Wc, bcA, out);
    }
}